// Round 5
// baseline (755.142 us; speedup 1.0000x reference)
//
#include <hip/hip_runtime.h>

// ---------------------------------------------------------------------------
// CA2_82300163326041: dual cross-attention fusion, MI355X bf16-MFMA pipeline.
//   k1 q_gemm  : Qcat[16384,1024](bf16) = [X|Y] @ [W_xq|W_yq]^T + bias
//   k2 kv_gemm : Kf[16384,512](bf16), Vt[8][512][2048](bf16, transposed V_f)
//   k3 attn    : PRODUCER/CONSUMER waves. WG = 384 thr = 6 waves, 64 q-rows.
//     producers (wv 0,1): 32q each; QK via B-frag reuse across 2 q-tiles
//       (32 LDS reads : 64 MFMA = 2:1), static-max exp2, publish P + row-sums.
//       aq = 128 VGPR, no O accumulator.
//     consumers (wv 2..5): 128-d slice each; PV one block behind (Pl dbuf),
//       V-frags direct from global/L2, K-DMA staging. acc = 128 AGPR, no aq.
//     One barrier/iter. LDS reads/WG/iter: 80 vs 144 in the symmetric design.
//   k4 add     : out = X + Y + attn0 + attn1   (fp32)
// MFMA layouts (measured, guide §3): A[m=lane&15][k=quad*8+j],
// Bt[n=lane&15][k=quad*8+j], D: col=lane&15, row=quad*4+reg.
// ---------------------------------------------------------------------------

#define B_    8
#define S_    2048
#define D_    512
#define M_TOT (B_ * S_) /* 16384 */

typedef __bf16 bf16_t;
typedef __bf16 bf16x8 __attribute__((ext_vector_type(8)));
typedef __bf16 bf16x4 __attribute__((ext_vector_type(4)));
typedef float  f32x4  __attribute__((ext_vector_type(4)));

typedef __attribute__((address_space(1))) const void* gas_cv;
typedef __attribute__((address_space(3))) void*       las_v;

__device__ __forceinline__ f32x4 mfma16(bf16x8 a, bf16x8 b, f32x4 c) {
    return __builtin_amdgcn_mfma_f32_16x16x32_bf16(a, b, c, 0, 0, 0);
}
__device__ __forceinline__ void load_lds16(const void* g, void* l) {
    __builtin_amdgcn_global_load_lds((gas_cv)g, (las_v)l, 16, 0, 0);
}

// ---------------------------------------------------------------------------
// k1: Qcat = [X|Y] @ [W_xq|W_yq]^T + bias. 128x128 tile, BK=32, fp32->bf16
// conversion during LDS staging.
// ---------------------------------------------------------------------------
__global__ __launch_bounds__(256) void k_qgemm(
    const float* __restrict__ X, const float* __restrict__ Y,
    const float* __restrict__ Wxq, const float* __restrict__ bxq,
    const float* __restrict__ Wyq, const float* __restrict__ byq,
    bf16_t* __restrict__ Qcat)
{
    __shared__ __attribute__((aligned(16))) bf16_t Al[128 * 40];
    __shared__ __attribute__((aligned(16))) bf16_t Bl[128 * 40];
    const int m0 = blockIdx.x * 128;
    const int n0 = blockIdx.y * 128;           // N = 1024 (Q1 | Q2)
    const bool second = (n0 >= 512);
    const float* A    = second ? Y : X;
    const float* W    = second ? Wyq : Wxq;
    const float* bias = second ? byq : bxq;
    const int nw = n0 & 511;
    const int t    = threadIdx.x;
    const int lane = t & 63;
    const int wv   = t >> 6;
    const int wm   = (wv & 1) * 64;
    const int wn   = (wv >> 1) * 64;
    const int l15  = lane & 15;
    const int quad = lane >> 4;

    f32x4 acc[4][4] = {};

    for (int k0 = 0; k0 < 512; k0 += 32) {
        __syncthreads();
#pragma unroll
        for (int p = 0; p < 4; ++p) {
            const int lin = p * 256 + t;
            const int row = lin >> 3;
            const int ch  = (lin & 7) * 4;
            const float4 va = *(const float4*)(A + (size_t)(m0 + row) * 512 + k0 + ch);
            bf16x4 pa = { (bf16_t)va.x, (bf16_t)va.y, (bf16_t)va.z, (bf16_t)va.w };
            *(bf16x4*)(Al + row * 40 + ch) = pa;
            const float4 vb = *(const float4*)(W + (size_t)(nw + row) * 512 + k0 + ch);
            bf16x4 pb = { (bf16_t)vb.x, (bf16_t)vb.y, (bf16_t)vb.z, (bf16_t)vb.w };
            *(bf16x4*)(Bl + row * 40 + ch) = pb;
        }
        __syncthreads();
        bf16x8 af[4], bfr[4];
#pragma unroll
        for (int i = 0; i < 4; ++i)
            af[i] = *(const bf16x8*)(Al + (wm + i * 16 + l15) * 40 + quad * 8);
#pragma unroll
        for (int i = 0; i < 4; ++i)
            bfr[i] = *(const bf16x8*)(Bl + (wn + i * 16 + l15) * 40 + quad * 8);
#pragma unroll
        for (int mt = 0; mt < 4; ++mt)
#pragma unroll
            for (int nt = 0; nt < 4; ++nt)
                acc[mt][nt] = mfma16(af[mt], bfr[nt], acc[mt][nt]);
    }

#pragma unroll
    for (int nt = 0; nt < 4; ++nt) {
        const int col  = n0 + wn + nt * 16 + l15;
        const float bv = bias[col & 511];
#pragma unroll
        for (int mt = 0; mt < 4; ++mt) {
            const int rowb = m0 + wm + mt * 16 + quad * 4;
#pragma unroll
            for (int r = 0; r < 4; ++r)
                Qcat[(size_t)(rowb + r) * 1024 + col] = (bf16_t)(acc[mt][nt][r] + bv);
        }
    }
}

// ---------------------------------------------------------------------------
// k2: [Kf | Vf] = Qcat @ [W_fk | W_fv]^T + bias.  K=1024.  Kf row-major.
// Vf stored TRANSPOSED per batch Vt[b][d][s]; tile transposed through LDS.
// ---------------------------------------------------------------------------
__global__ __launch_bounds__(256) void k_kvgemm(
    const bf16_t* __restrict__ Qcat,
    const float* __restrict__ Wfk, const float* __restrict__ bfk,
    const float* __restrict__ Wfv, const float* __restrict__ bfv,
    bf16_t* __restrict__ Kf, bf16_t* __restrict__ Vt)
{
    __shared__ __attribute__((aligned(16))) union {
        struct { bf16_t Al[128 * 40]; bf16_t Bl[128 * 40]; } g;
        bf16_t T[128 * 132];   // [d_local][s_local], pad 128->132
    } sm;
    const int m0 = blockIdx.x * 128;
    const int n0 = blockIdx.y * 128;           // N = 1024 (Kf | Vf)
    const bool isV = (n0 >= 512);
    const float* W    = isV ? Wfv : Wfk;
    const float* bias = isV ? bfv : bfk;
    const int nw = n0 & 511;
    const int t    = threadIdx.x;
    const int lane = t & 63;
    const int wv   = t >> 6;
    const int wm   = (wv & 1) * 64;
    const int wn   = (wv >> 1) * 64;
    const int l15  = lane & 15;
    const int quad = lane >> 4;

    f32x4 acc[4][4] = {};

    for (int k0 = 0; k0 < 1024; k0 += 32) {
        __syncthreads();
#pragma unroll
        for (int p = 0; p < 2; ++p) {          // A: bf16 copy 128x32
            const int lin = p * 256 + t;
            const int row = lin >> 2;
            const int ch  = (lin & 3) * 8;
            *(bf16x8*)(sm.g.Al + row * 40 + ch) =
                *(const bf16x8*)(Qcat + (size_t)(m0 + row) * 1024 + k0 + ch);
        }
#pragma unroll
        for (int p = 0; p < 4; ++p) {          // B: fp32->bf16 128x32
            const int lin = p * 256 + t;
            const int row = lin >> 3;
            const int ch  = (lin & 7) * 4;
            const float4 vb = *(const float4*)(W + (size_t)(nw + row) * 1024 + k0 + ch);
            bf16x4 pb = { (bf16_t)vb.x, (bf16_t)vb.y, (bf16_t)vb.z, (bf16_t)vb.w };
            *(bf16x4*)(sm.g.Bl + row * 40 + ch) = pb;
        }
        __syncthreads();
        bf16x8 af[4], bfr[4];
#pragma unroll
        for (int i = 0; i < 4; ++i)
            af[i] = *(const bf16x8*)(sm.g.Al + (wm + i * 16 + l15) * 40 + quad * 8);
#pragma unroll
        for (int i = 0; i < 4; ++i)
            bfr[i] = *(const bf16x8*)(sm.g.Bl + (wn + i * 16 + l15) * 40 + quad * 8);
#pragma unroll
        for (int mt = 0; mt < 4; ++mt)
#pragma unroll
            for (int nt = 0; nt < 4; ++nt)
                acc[mt][nt] = mfma16(af[mt], bfr[nt], acc[mt][nt]);
    }

    if (!isV) {
#pragma unroll
        for (int nt = 0; nt < 4; ++nt) {
            const int col  = n0 + wn + nt * 16 + l15;   // < 512
            const float bv = bias[col];
#pragma unroll
            for (int mt = 0; mt < 4; ++mt) {
                const int rowb = m0 + wm + mt * 16 + quad * 4;
#pragma unroll
                for (int r = 0; r < 4; ++r)
                    Kf[(size_t)(rowb + r) * 512 + col] = (bf16_t)(acc[mt][nt][r] + bv);
            }
        }
    } else {
        __syncthreads();   // staging reads of the last k-block are done
#pragma unroll
        for (int nt = 0; nt < 4; ++nt) {
            const int dl = wn + nt * 16 + l15;
            const float bv = bias[nw + dl];
#pragma unroll
            for (int mt = 0; mt < 4; ++mt) {
                const int sl = wm + mt * 16 + quad * 4;
#pragma unroll
                for (int r = 0; r < 4; ++r)
                    sm.T[dl * 132 + sl + r] = (bf16_t)(acc[mt][nt][r] + bv);
            }
        }
        __syncthreads();
        const int bb = m0 >> 11;             // batch
        const int sb = m0 & 2047;
        const int half = lane >> 5;
        const int sl4  = (lane & 31) * 4;
#pragma unroll
        for (int i = 0; i < 16; ++i) {
            const int dl = wv * 32 + i * 2 + half;
            const bf16x4 v = *(const bf16x4*)(sm.T + dl * 132 + sl4);
            *(bf16x4*)(Vt + (size_t)(bb * 512 + nw + dl) * 2048 + sb + sl4) = v;
        }
    }
}

// ---------------------------------------------------------------------------
// k3: producer/consumer attention. 384 threads = 6 waves per 64-q-row WG.
//   waves 0,1 (producers, p=wv): QK for q rows [q0+p*32, +32), static-max
//     exp2 softmax numerators -> Pl[cur]; per-lane row-sum accumulation.
//   waves 2..5 (consumers, cv=wv-2): stage K(kb+1) DMA (8 rows each),
//     PV(kb-1) for d-slice [cv*128, +128) with V-frags from global Vt.
//   One __syncthreads per iter staggers producers (block kb) ahead of
//   consumers (block kb-1) on the Pl double buffer.
// mode 0: attn[w] = O (bf16); mode 1: out = X+Y+O; mode 2: out += O.
// ---------------------------------------------------------------------------
__global__ __launch_bounds__(384, 2) void k_attn(
    const bf16_t* __restrict__ Qcat, const bf16_t* __restrict__ Kf,
    const bf16_t* __restrict__ Vt,
    const float* __restrict__ X, const float* __restrict__ Y,
    float* __restrict__ out, bf16_t* __restrict__ attn,
    const int mode, const int which)
{
    __shared__ __attribute__((aligned(16))) bf16_t Kl[2][32 * 520];
    __shared__ __attribute__((aligned(16))) bf16_t Pl[2][64 * 40];
    __shared__ float lsumL[64];

    const int b = blockIdx.y;
    const int w = (mode == 0) ? (int)blockIdx.z : which;
    const int t    = threadIdx.x;
    const int lane = t & 63;
    const int wv   = t >> 6;
    const int l15  = lane & 15;
    const int quad = lane >> 4;
    const int q0   = blockIdx.x * 64;        // WG q-tile base
    const bool prod = (wv < 2);
    const int p  = wv;                       // producer id 0,1
    const int cv = wv - 2;                   // consumer id 0..3

    const bf16_t* Kbase = Kf + (size_t)b * S_ * 512;
    const bf16_t* Vbase = Vt + ((size_t)b * 512 + cv * 128) * S_;

    // exp2 domain: 1/sqrt(512) * log2(e)
    const float sc2 = 0.04419417382415922f * 1.4426950408889634f;

    // producer state: Q fragments for 32 q-rows (2 q-tiles), full K=512
    bf16x8 aq[2][16];
    f32x4  lacc[2] = {};                     // row-sum partials [qt][r]
    if (prod) {
        const bf16_t* qp = Qcat + (size_t)(b * S_ + q0 + p * 32 + l15) * 1024
                         + w * 512 + quad * 8;
#pragma unroll
        for (int qt = 0; qt < 2; ++qt)
#pragma unroll
            for (int ks = 0; ks < 16; ++ks)
                aq[qt][ks] = *(const bf16x8*)(qp + qt * 16 * 1024 + ks * 32);
    }

    // consumer state: O accumulator [qt 0..3][dt 0..7]
    f32x4 acc[4][8] = {};

    // ---- prologue: consumers stage K0 -> Kl[0] (8 rows each)
    if (!prod) {
#pragma unroll
        for (int i = 0; i < 8; ++i) {
            const int row = cv * 8 + i;
            load_lds16(Kbase + (size_t)row * 512 + lane * 8, Kl[0] + row * 520);
        }
    }
    __syncthreads();

    // ---- peeled iter 0: producers QK(0) -> Pl[0]; consumers DMA K1
    if (prod) {
        f32x4 s[2][2] = {};
#pragma unroll
        for (int ks = 0; ks < 16; ++ks) {
            const bf16x8 bk0 = *(const bf16x8*)(Kl[0] + l15 * 520 + ks * 32 + quad * 8);
            const bf16x8 bk1 = *(const bf16x8*)(Kl[0] + (16 + l15) * 520 + ks * 32 + quad * 8);
            s[0][0] = mfma16(aq[0][ks], bk0, s[0][0]);
            s[0][1] = mfma16(aq[0][ks], bk1, s[0][1]);
            s[1][0] = mfma16(aq[1][ks], bk0, s[1][0]);
            s[1][1] = mfma16(aq[1][ks], bk1, s[1][1]);
        }
#pragma unroll
        for (int qt = 0; qt < 2; ++qt)
#pragma unroll
            for (int r = 0; r < 4; ++r) {
                const float p0 = exp2f(s[qt][0][r] * sc2);
                const float p1 = exp2f(s[qt][1][r] * sc2);
                lacc[qt][r] += p0 + p1;
                const int row = p * 32 + qt * 16 + quad * 4 + r;
                Pl[0][row * 40 + l15] = (bf16_t)p0;
                Pl[0][row * 40 + 16 + l15] = (bf16_t)p1;
            }
    } else {
#pragma unroll
        for (int i = 0; i < 8; ++i) {
            const int row = cv * 8 + i;
            load_lds16(Kbase + (size_t)(32 + row) * 512 + lane * 8, Kl[1] + row * 520);
        }
    }
    __syncthreads();

    // ---- main loop kb = 1..63: producers QK(kb); consumers DMA K(kb+1)
    //      + PV(kb-1). kb=63's DMA prefetches harmless in-bounds ws bytes.
    for (int kb = 1; kb < 64; ++kb) {
        const int cur = kb & 1;
        const int prv = cur ^ 1;

        if (prod) {
            f32x4 s[2][2] = {};
#pragma unroll
            for (int ks = 0; ks < 16; ++ks) {
                const bf16x8 bk0 = *(const bf16x8*)(Kl[cur] + l15 * 520 + ks * 32 + quad * 8);
                const bf16x8 bk1 = *(const bf16x8*)(Kl[cur] + (16 + l15) * 520 + ks * 32 + quad * 8);
                s[0][0] = mfma16(aq[0][ks], bk0, s[0][0]);
                s[0][1] = mfma16(aq[0][ks], bk1, s[0][1]);
                s[1][0] = mfma16(aq[1][ks], bk0, s[1][0]);
                s[1][1] = mfma16(aq[1][ks], bk1, s[1][1]);
            }
#pragma unroll
            for (int qt = 0; qt < 2; ++qt)
#pragma unroll
                for (int r = 0; r < 4; ++r) {
                    const float p0 = exp2f(s[qt][0][r] * sc2);
                    const float p1 = exp2f(s[qt][1][r] * sc2);
                    lacc[qt][r] += p0 + p1;
                    const int row = p * 32 + qt * 16 + quad * 4 + r;
                    Pl[cur][row * 40 + l15] = (bf16_t)p0;
                    Pl[cur][row * 40 + 16 + l15] = (bf16_t)p1;
                }
        } else {
            // stage K(kb+1) into Kl[prv]
            const bf16_t* src = Kbase + (size_t)(kb + 1) * 32 * 512;
#pragma unroll
            for (int i = 0; i < 8; ++i) {
                const int row = cv * 8 + i;
                load_lds16(src + (size_t)row * 512 + lane * 8, Kl[prv] + row * 520);
            }
            // V fragments for PV(kb-1)
            bf16x8 vb[8];
#pragma unroll
            for (int i = 0; i < 8; ++i)
                vb[i] = *(const bf16x8*)(Vbase + (size_t)(i * 16 + l15) * S_ +
                                         (kb - 1) * 32 + quad * 8);
            // P fragments (A-layout) from Pl[prv]
            bf16x8 ap[4];
#pragma unroll
            for (int qt = 0; qt < 4; ++qt)
                ap[qt] = *(const bf16x8*)(Pl[prv] + (qt * 16 + l15) * 40 + quad * 8);
#pragma unroll
            for (int dt = 0; dt < 8; ++dt)
#pragma unroll
                for (int qt = 0; qt < 4; ++qt)
                    acc[qt][dt] = mfma16(ap[qt], vb[dt], acc[qt][dt]);
        }

        __syncthreads();
    }

    // ---- producers publish row sums (sum over 16 l15 lanes)
    if (prod) {
#pragma unroll
        for (int qt = 0; qt < 2; ++qt) {
#pragma unroll
            for (int r = 0; r < 4; ++r) {
                float v = lacc[qt][r];
#pragma unroll
                for (int off = 1; off < 16; off <<= 1) v += __shfl_xor(v, off, 64);
                if (l15 == 0) lsumL[p * 32 + qt * 16 + quad * 4 + r] = v;
            }
        }
    }
    __syncthreads();

    // ---- consumers: PV(63) from Pl[1], then normalize + store
    if (!prod) {
        bf16x8 vb[8];
#pragma unroll
        for (int i = 0; i < 8; ++i)
            vb[i] = *(const bf16x8*)(Vbase + (size_t)(i * 16 + l15) * S_ +
                                     63 * 32 + quad * 8);
        bf16x8 ap[4];
#pragma unroll
        for (int qt = 0; qt < 4; ++qt)
            ap[qt] = *(const bf16x8*)(Pl[1] + (qt * 16 + l15) * 40 + quad * 8);
#pragma unroll
        for (int dt = 0; dt < 8; ++dt)
#pragma unroll
            for (int qt = 0; qt < 4; ++qt)
                acc[qt][dt] = mfma16(ap[qt], vb[dt], acc[qt][dt]);

#pragma unroll
        for (int qt = 0; qt < 4; ++qt) {
            f32x4 inv;
#pragma unroll
            for (int r = 0; r < 4; ++r) inv[r] = 1.0f / lsumL[qt * 16 + quad * 4 + r];
#pragma unroll
            for (int dt = 0; dt < 8; ++dt) {
                const int d = cv * 128 + dt * 16 + l15;
#pragma unroll
                for (int r = 0; r < 4; ++r) {
                    const float v = acc[qt][dt][r] * inv[r];
                    const size_t idx =
                        (size_t)(b * S_ + q0 + qt * 16 + quad * 4 + r) * 512 + d;
                    if (mode == 0)      attn[(size_t)w * M_TOT * 512 + idx] = (bf16_t)v;
                    else if (mode == 1) out[idx] = X[idx] + Y[idx] + v;
                    else                out[idx] += v;
                }
            }
        }
    }
}

// ---------------------------------------------------------------------------
// k4: out = X + Y + attn0 + attn1
// ---------------------------------------------------------------------------
__global__ __launch_bounds__(256) void k_add(
    const float* __restrict__ X, const float* __restrict__ Y,
    const bf16_t* __restrict__ a0, const bf16_t* __restrict__ a1,
    float* __restrict__ out)
{
    const size_t i = ((size_t)blockIdx.x * 256 + threadIdx.x) * 4;
    const float4 x = *(const float4*)(X + i);
    const float4 y = *(const float4*)(Y + i);
    const bf16x4 v0 = *(const bf16x4*)(a0 + i);
    const bf16x4 v1 = *(const bf16x4*)(a1 + i);
    float4 o;
    o.x = x.x + y.x + (float)v0[0] + (float)v1[0];
    o.y = x.y + y.y + (float)v0[1] + (float)v1[1];
    o.z = x.z + y.z + (float)v0[2] + (float)v1[2];
    o.w = x.w + y.w + (float)v0[3] + (float)v1[3];
    *(float4*)(out + i) = o;
}

extern "C" void kernel_launch(void* const* d_in, const int* in_sizes, int n_in,
                              void* d_out, int out_size, void* d_ws, size_t ws_size,
                              hipStream_t stream)
{
    const float* X   = (const float*)d_in[0];
    const float* Y   = (const float*)d_in[1];
    const float* Wxq = (const float*)d_in[2];
    const float* bxq = (const float*)d_in[3];
    const float* Wyq = (const float*)d_in[4];
    const float* byq = (const float*)d_in[5];
    const float* Wfk = (const float*)d_in[6];
    const float* bfk = (const float*)d_in[7];
    const float* Wfv = (const float*)d_in[8];
    const float* bfv = (const float*)d_in[9];
    float* out = (float*)d_out;
    char*  ws  = (char*)d_ws;

    // ws layout (bytes): Qcat 32MiB | Kf 16MiB | Vt 16MiB | attn 2x16MiB
    bf16_t* Qcat = (bf16_t*)(ws);
    bf16_t* Kf   = (bf16_t*)(ws + (size_t)33554432);
    bf16_t* Vt   = (bf16_t*)(ws + (size_t)50331648);
    bf16_t* attn = (bf16_t*)(ws + (size_t)67108864);
    const bool big = ws_size >= (size_t)100663296;

    k_qgemm<<<dim3(128, 8), 256, 0, stream>>>(X, Y, Wxq, bxq, Wyq, byq, Qcat);
    k_kvgemm<<<dim3(128, 8), 256, 0, stream>>>(Qcat, Wfk, bfk, Wfv, bfv, Kf, Vt);
    if (big) {
        k_attn<<<dim3(32, 8, 2), 384, 0, stream>>>(Qcat, Kf, Vt, X, Y, out, attn, 0, 0);
        k_add<<<dim3(8192), 256, 0, stream>>>(X, Y, attn, attn + (size_t)M_TOT * 512, out);
    } else {
        k_attn<<<dim3(32, 8, 1), 384, 0, stream>>>(Qcat, Kf, Vt, X, Y, out, attn, 1, 0);
        k_attn<<<dim3(32, 8, 1), 384, 0, stream>>>(Qcat, Kf, Vt, X, Y, out, attn, 2, 1);
    }
}